// Round 11
// baseline (901.429 us; speedup 1.0000x reference)
//
#include <hip/hip_runtime.h>
#include <hip/hip_cooperative_groups.h>

namespace cg = cooperative_groups;

#define NN 100000
#define NE 1600000
#define DD 128
#define NCB 196     // coarse buckets, 512 nodes each (dst >> 9)
#define TILE 2048   // edges per xbh hist tile
#define NTILE 782   // ceil(NE/TILE)
#define TILEC 4096  // edges per cscatter tile (long write segments)
#define NTILEC 391  // ceil(NE/TILEC)
#define FCAP 12288  // fsort LDS edge capacity (mean 8163, +45 sigma)
#define SREP 32     // stats replicas (kills global-atomic line contention)
#define WPAD 17408  // padded bf16 W: 128 rows * 136 ushorts
#define GROWS 256   // rows per GEMM tile (4 sub-tiles of 64)
#define GBLK 391    // ceil(NN/GROWS)

typedef __attribute__((ext_vector_type(8))) short bf16x8;
typedef __attribute__((ext_vector_type(4))) float f32x4;

union u4bf8 { uint4 u; bf16x8 v; };

__device__ __forceinline__ ushort f2bf(float f) {
    union { float f; uint i; } v; v.f = f;
    uint i = v.i;
    return (ushort)((i + 0x7fffu + ((i >> 16) & 1u)) >> 16);
}
__device__ __forceinline__ float bf2f(ushort u) {
    union { uint i; float f; } v; v.i = ((uint)u) << 16; return v.f;
}
__device__ __forceinline__ float blo(uint v) { return bf2f((ushort)(v & 0xffffu)); }
__device__ __forceinline__ float bhi(uint v) { return bf2f((ushort)(v >> 16)); }

// fused: bf16 conversion of x -> xb + coarse dst histogram + bf16 W prep
__global__ __launch_bounds__(256) void k_xbh(const float* __restrict__ x,
                                             uint* __restrict__ xb,
                                             const int* __restrict__ ei,
                                             int* __restrict__ ghistP,
                                             const float* __restrict__ W1,
                                             const float* __restrict__ W2,
                                             const float* __restrict__ W3,
                                             ushort* __restrict__ Wbp) {
    __shared__ int h[NCB];
    int t = threadIdx.x;
    if (t < NCB) h[t] = 0;
    __syncthreads();
    int base = blockIdx.x * TILE;
#pragma unroll
    for (int i = 0; i < 8; ++i) {
        int e = base + i * 256 + t;
        if (e < NE) atomicAdd(&h[ei[NE + e] >> 9], 1);
    }
    int gid = blockIdx.x * 256 + t;
#pragma unroll
    for (int i = 0; i < 8; ++i) {
        int item = i * (NTILE * 256) + gid;
        if (item < NN * 16) {
            int n = item >> 4, q = item & 15;
            const float* xp = x + (size_t)n * DD + q * 8;
            float4 a = *(const float4*)xp;
            float4 b = *(const float4*)(xp + 4);
            uint4 pk;
            pk.x = (uint)f2bf(a.x) | ((uint)f2bf(a.y) << 16);
            pk.y = (uint)f2bf(a.z) | ((uint)f2bf(a.w) << 16);
            pk.z = (uint)f2bf(b.x) | ((uint)f2bf(b.y) << 16);
            pk.w = (uint)f2bf(b.z) | ((uint)f2bf(b.w) << 16);
            *(uint4*)(xb + (size_t)n * 64 + q * 4) = pk;
        }
    }
    // first 24 blocks also convert W1|W2|W3 (f32) into padded bf16 (136-stride)
    int c = gid;
    if (c < 6144) {
        int l = c >> 11;             // 2048 8-float chunks per 128x128 layer
        int cc = c & 2047;
        int r = cc >> 4, c8 = (cc & 15) * 8;
        const float* Wl = (l == 0) ? W1 : (l == 1) ? W2 : W3;
        const float* p = Wl + r * DD + c8;
        float4 a = *(const float4*)p;
        float4 b = *(const float4*)(p + 4);
        uint4 pk;
        pk.x = (uint)f2bf(a.x) | ((uint)f2bf(a.y) << 16);
        pk.y = (uint)f2bf(a.z) | ((uint)f2bf(a.w) << 16);
        pk.z = (uint)f2bf(b.x) | ((uint)f2bf(b.y) << 16);
        pk.w = (uint)f2bf(b.z) | ((uint)f2bf(b.w) << 16);
        *(uint4*)&Wbp[(size_t)l * WPAD + r * 136 + c8] = pk;
    }
    __syncthreads();
    if (t < NCB && h[t] > 0) atomicAdd(&ghistP[t * 16], h[t]);
}

// bucketize edges by coarse dst; packed val = src | (dst&511)<<17
// bucket bases computed by LOCAL scan of ghistP; cursors start at 0 (memset).
__global__ __launch_bounds__(256) void k_cscatter(const int* __restrict__ ei,
                                                  const int* __restrict__ ghistP,
                                                  int* __restrict__ gcurP,
                                                  uint* __restrict__ buck) {
    __shared__ int h[NCB];
    __shared__ int tb[NCB];
    __shared__ int sh[256];
    int t = threadIdx.x;
    if (t < NCB) h[t] = 0;
    __syncthreads();
    int base = blockIdx.x * TILEC;
    uint vv[16]; int bb[16]; int rr[16];
#pragma unroll
    for (int i = 0; i < 16; ++i) {
        int e = base + i * 256 + t;
        bb[i] = -1;
        if (e < NE) {
            int s = ei[e], d = ei[NE + e];
            int b = d >> 9;
            bb[i] = b;
            vv[i] = (uint)s | ((uint)(d & 511) << 17);
            rr[i] = atomicAdd(&h[b], 1);
        }
    }
    __syncthreads();
    int my = (t < NCB) ? ghistP[t * 16] : 0;
    sh[t] = my;
    __syncthreads();
    for (int o = 1; o < 256; o <<= 1) {
        int u = (t >= o) ? sh[t - o] : 0;
        __syncthreads();
        sh[t] += u;
        __syncthreads();
    }
    if (t < NCB && h[t] > 0)
        tb[t] = (sh[t] - my) + atomicAdd(&gcurP[t * 16], h[t]);
    __syncthreads();
#pragma unroll
    for (int i = 0; i < 16; ++i) {
        if (bb[i] >= 0) buck[tb[bb[i]] + rr[i]] = vv[i];
    }
}

// one block per coarse bucket: bases from local scan, segment staged in LDS,
// fine 512-node hist + scan, write rowp, scatter into node-sorted csr
__global__ __launch_bounds__(256) void k_fsort(const uint* __restrict__ buck,
                                               const int* __restrict__ ghistP,
                                               int* __restrict__ csr,
                                               int* __restrict__ rowp) {
    __shared__ uint ebuf[FCAP];
    __shared__ int cnt[512];
    __shared__ int sd[256];
    __shared__ int sh[256];
    int c = blockIdx.x, t = threadIdx.x;
    cnt[t] = 0; cnt[t + 256] = 0;
    int my = (t < NCB) ? ghistP[t * 16] : 0;
    sh[t] = my;
    __syncthreads();
    for (int o = 1; o < 256; o <<= 1) {
        int u = (t >= o) ? sh[t - o] : 0;
        __syncthreads();
        sh[t] += u;
        __syncthreads();
    }
    int s1 = sh[c];
    int hc = ghistP[c * 16];
    int s0 = s1 - hc;
    int len = hc;
    int cap = (len < FCAP) ? len : FCAP;
    for (int i = t; i < cap; i += 256) ebuf[i] = buck[s0 + i];
    __syncthreads();
    for (int i = t; i < len; i += 256) {
        uint v = (i < FCAP) ? ebuf[i] : buck[s0 + i];
        atomicAdd(&cnt[(v >> 17) & 511], 1);
    }
    __syncthreads();
    int p = cnt[2 * t], q = cnt[2 * t + 1];
    sd[t] = p + q;
    __syncthreads();
    for (int o = 1; o < 256; o <<= 1) {
        int u = (t >= o) ? sd[t - o] : 0;
        __syncthreads();
        sd[t] += u;
        __syncthreads();
    }
    int base = sd[t] - (p + q);
    rowp[c * 512 + 2 * t]     = s0 + base;
    rowp[c * 512 + 2 * t + 1] = s0 + base + p;
    __syncthreads();
    cnt[2 * t] = base;
    cnt[2 * t + 1] = base + p;
    __syncthreads();
    for (int i = t; i < len; i += 256) {
        uint v = (i < FCAP) ? ebuf[i] : buck[s0 + i];
        int ld = (int)((v >> 17) & 511u);
        int pos = atomicAdd(&cnt[ld], 1);
        csr[s0 + pos] = (int)(v & 0x1FFFFu);
    }
}

#define B8(ACC0, ACC1, SJ, J)                                               \
    {                                                                       \
        int s0 = __shfl(SJ, J),     s1 = __shfl(SJ, J + 1);                 \
        int s2 = __shfl(SJ, J + 2), s3 = __shfl(SJ, J + 3);                 \
        int s4 = __shfl(SJ, J + 4), s5 = __shfl(SJ, J + 5);                 \
        int s6 = __shfl(SJ, J + 6), s7 = __shfl(SJ, J + 7);                 \
        uint v0 = xb[(size_t)s0 * 64 + lane], v1 = xb[(size_t)s1 * 64 + lane]; \
        uint v2 = xb[(size_t)s2 * 64 + lane], v3 = xb[(size_t)s3 * 64 + lane]; \
        uint v4 = xb[(size_t)s4 * 64 + lane], v5 = xb[(size_t)s5 * 64 + lane]; \
        uint v6 = xb[(size_t)s6 * 64 + lane], v7 = xb[(size_t)s7 * 64 + lane]; \
        ACC0 += blo(v0) + blo(v1) + blo(v2) + blo(v3)                       \
              + blo(v4) + blo(v5) + blo(v6) + blo(v7);                      \
        ACC1 += bhi(v0) + bhi(v1) + bhi(v2) + bhi(v3)                       \
              + bhi(v4) + bhi(v5) + bhi(v6) + bhi(v7);                      \
    }

// GEMM phase body (one 256-row tile), shared buffers passed in.
template <int MODE>
__device__ void gemm_phase(const ushort* __restrict__ Ain,
                           const ushort* __restrict__ Wp,
                           const float* __restrict__ bias,
                           const float* __restrict__ statsIn,
                           const float* __restrict__ g,
                           const float* __restrict__ be,
                           void* __restrict__ Outv,
                           float* __restrict__ statsOut,
                           ushort* lw, float (*red)[4][DD], float* lac) {
    int tid = threadIdx.x;
    int wave = tid >> 6, lane = tid & 63;
    int lm = lane & 15, quad = lane >> 4;
    ushort* Out16 = (ushort*)Outv;
    float* Out32 = (float*)Outv;

    for (int tile = blockIdx.x; tile < GBLK; tile += gridDim.x) {
        // issue sub-tile-0 A loads first (overlap with W staging)
        int row00 = tile * GROWS + wave * 16;
        int ar0 = (row00 + lm < NN) ? row00 + lm : 0;
        uint4 araw[4];
#pragma unroll
        for (int kb = 0; kb < 4; ++kb)
            araw[kb] = *(const uint4*)(Ain + (size_t)ar0 * DD + kb * 32 + quad * 8);

#pragma unroll
        for (int it = 0; it < 8; ++it) {
            int o8 = (it * 256 + tid) * 8;
            *(uint4*)&lw[o8] = *(const uint4*)&Wp[o8];
        }
        if (tid < 128) {
            int o8 = 16384 + tid * 8;
            *(uint4*)&lw[o8] = *(const uint4*)&Wp[o8];
        }
        if constexpr (MODE != 1) {
            if (tid < DD) {
                float S = 0.f, Q = 0.f;
#pragma unroll
                for (int r = 0; r < SREP; ++r) {
                    S += statsIn[(r << 8) + tid];
                    Q += statsIn[(r << 8) + DD + tid];
                }
                float inv = 1.f / (float)NN;
                float mean = S * inv;
                float var = Q * inv - mean * mean;
                float a = g[tid] * rsqrtf(var + 1e-5f);
                lac[tid] = a;
                lac[DD + tid] = be[tid] - mean * a;
            }
        }
        __syncthreads();

        float csum[8], csq[8];
#pragma unroll
        for (int nt = 0; nt < 8; ++nt) { csum[nt] = 0.f; csq[nt] = 0.f; }

#pragma unroll
        for (int sub = 0; sub < 4; ++sub) {
            int row0 = tile * GROWS + sub * 64 + wave * 16;
            int arow = row0 + lm;
            int ar = (arow < NN) ? arow : 0;

            bf16x8 afrag[4];
#pragma unroll
            for (int kb = 0; kb < 4; ++kb) {
                int k0 = kb * 32 + quad * 8;
                u4bf8 u;
                if (sub == 0) u.u = araw[kb];
                else          u.u = *(const uint4*)(Ain + (size_t)ar * DD + k0);
                if constexpr (MODE == 1) {
                    afrag[kb] = u.v;
                } else {
                    uint pk[4] = {u.u.x, u.u.y, u.u.z, u.u.w};
                    bf16x8 af;
#pragma unroll
                    for (int jj = 0; jj < 4; ++jj) {
                        int k = k0 + jj * 2;
                        float v0 = blo(pk[jj]);
                        float v1 = bhi(pk[jj]);
                        v0 = fmaxf(fmaf(v0, lac[k], lac[DD + k]), 0.f);
                        v1 = fmaxf(fmaf(v1, lac[k + 1], lac[DD + k + 1]), 0.f);
                        af[jj * 2]     = (short)f2bf(v0);
                        af[jj * 2 + 1] = (short)f2bf(v1);
                    }
                    afrag[kb] = af;
                }
            }

            f32x4 acc[8];
#pragma unroll
            for (int nt = 0; nt < 8; ++nt) {
                float bv = (MODE == 3) ? 0.f : bias[nt * 16 + lm];
                acc[nt] = (f32x4){bv, bv, bv, bv};
            }

#pragma unroll
            for (int kb = 0; kb < 4; ++kb) {
#pragma unroll
                for (int nt = 0; nt < 8; ++nt) {
                    bf16x8 bfrag = *(const bf16x8*)&lw[(nt * 16 + lm) * 136 + kb * 32 + quad * 8];
                    acc[nt] = __builtin_amdgcn_mfma_f32_16x16x32_bf16(afrag[kb], bfrag, acc[nt], 0, 0, 0);
                }
            }

#pragma unroll
            for (int nt = 0; nt < 8; ++nt) {
                int col = nt * 16 + lm;
#pragma unroll
                for (int r = 0; r < 4; ++r) {
                    int row = row0 + quad * 4 + r;
                    float v = acc[nt][r];
                    if (MODE == 3) v = fmaxf(v, 0.f);
                    if (row < NN) {
                        if constexpr (MODE == 3) Out32[(size_t)row * DD + col] = v;
                        else Out16[(size_t)row * DD + col] = f2bf(v);
                        csum[nt] += v;
                        csq[nt] += v * v;
                    }
                }
            }
        }

        if constexpr (MODE != 3) {
#pragma unroll
            for (int nt = 0; nt < 8; ++nt) {
                float s = csum[nt], q = csq[nt];
                s += __shfl_down(s, 16, 64); q += __shfl_down(q, 16, 64);
                s += __shfl_down(s, 32, 64); q += __shfl_down(q, 32, 64);
                if (quad == 0) {
                    red[0][wave][nt * 16 + lm] = s;
                    red[1][wave][nt * 16 + lm] = q;
                }
            }
            __syncthreads();
            if (tid < DD) {
                float S = red[0][0][tid] + red[0][1][tid] + red[0][2][tid] + red[0][3][tid];
                float Q = red[1][0][tid] + red[1][1][tid] + red[1][2][tid] + red[1][3][tid];
                int rep = (tile & (SREP - 1)) << 8;
                atomicAdd(&statsOut[rep + tid], S);
                atomicAdd(&statsOut[rep + DD + tid], Q);
            }
        }
        __syncthreads();   // lw/lac reuse safety for multi-tile fallback
    }
}

struct TailArgs {
    const uint* xb; const int* rowp; const int* csr; ushort* agg;
    const ushort* Wbp;
    const float* b1; const float* b2;
    const float* g1; const float* be1; const float* g2; const float* be2;
    ushort* t1; ushort* t2; float* outp;
    float* stats; float* stats2;
};

// cooperative tail: gather phase + 3 GEMM phases, grid.sync between.
__global__ __launch_bounds__(256, 4) void k_tail(TailArgs a) {
    __shared__ __align__(16) ushort lw[DD * 136];
    __shared__ float red[2][4][DD];
    __shared__ float lac[2 * DD];
    cg::grid_group grid = cg::this_grid();

    // ---- gather phase (grid-strided pairs) ----
    {
        const uint* __restrict__ xb = a.xb;
        const int* __restrict__ rowp = a.rowp;
        const int* __restrict__ csr = a.csr;
        ushort* __restrict__ agg = a.agg;
        const int HALF = NN / 2;
        int wave = threadIdx.x >> 6, lane = threadIdx.x & 63;
        int wstep = gridDim.x * 4;
        for (int w = blockIdx.x * 4 + wave; w < HALF; w += wstep) {
            int nA = w, nB = w + HALF;
            uint sA = xb[(size_t)nA * 64 + lane];
            uint sB = xb[(size_t)nB * 64 + lane];
            float a0 = blo(sA), a1 = bhi(sA);
            float b0 = blo(sB), b1 = bhi(sB);
            int iA = rowp[nA], eA = rowp[nA + 1];
            int iB = rowp[nB], eB = rowp[nB + 1];

            while (iA < eA || iB < eB) {
                int mA = eA - iA; if (mA > 64) mA = 64; if (mA < 0) mA = 0;
                int mB = eB - iB; if (mB > 64) mB = 64; if (mB < 0) mB = 0;
                int sjA = (lane < mA) ? csr[iA + lane] : 0;
                int sjB = (lane < mB) ? csr[iB + lane] : 0;
                int j = 0, k = 0;
                while (j + 8 <= mA && k + 8 <= mB) {
                    int t0 = __shfl(sjA, j),     t1 = __shfl(sjA, j + 1);
                    int t2 = __shfl(sjA, j + 2), t3 = __shfl(sjA, j + 3);
                    int t4 = __shfl(sjA, j + 4), t5 = __shfl(sjA, j + 5);
                    int t6 = __shfl(sjA, j + 6), t7 = __shfl(sjA, j + 7);
                    int u0 = __shfl(sjB, k),     u1 = __shfl(sjB, k + 1);
                    int u2 = __shfl(sjB, k + 2), u3 = __shfl(sjB, k + 3);
                    int u4 = __shfl(sjB, k + 4), u5 = __shfl(sjB, k + 5);
                    int u6 = __shfl(sjB, k + 6), u7 = __shfl(sjB, k + 7);
                    uint vA0 = xb[(size_t)t0 * 64 + lane], vA1 = xb[(size_t)t1 * 64 + lane];
                    uint vA2 = xb[(size_t)t2 * 64 + lane], vA3 = xb[(size_t)t3 * 64 + lane];
                    uint vA4 = xb[(size_t)t4 * 64 + lane], vA5 = xb[(size_t)t5 * 64 + lane];
                    uint vA6 = xb[(size_t)t6 * 64 + lane], vA7 = xb[(size_t)t7 * 64 + lane];
                    uint vB0 = xb[(size_t)u0 * 64 + lane], vB1 = xb[(size_t)u1 * 64 + lane];
                    uint vB2 = xb[(size_t)u2 * 64 + lane], vB3 = xb[(size_t)u3 * 64 + lane];
                    uint vB4 = xb[(size_t)u4 * 64 + lane], vB5 = xb[(size_t)u5 * 64 + lane];
                    uint vB6 = xb[(size_t)u6 * 64 + lane], vB7 = xb[(size_t)u7 * 64 + lane];
                    a0 += blo(vA0) + blo(vA1) + blo(vA2) + blo(vA3)
                        + blo(vA4) + blo(vA5) + blo(vA6) + blo(vA7);
                    a1 += bhi(vA0) + bhi(vA1) + bhi(vA2) + bhi(vA3)
                        + bhi(vA4) + bhi(vA5) + bhi(vA6) + bhi(vA7);
                    b0 += blo(vB0) + blo(vB1) + blo(vB2) + blo(vB3)
                        + blo(vB4) + blo(vB5) + blo(vB6) + blo(vB7);
                    b1 += bhi(vB0) + bhi(vB1) + bhi(vB2) + bhi(vB3)
                        + bhi(vB4) + bhi(vB5) + bhi(vB6) + bhi(vB7);
                    j += 8; k += 8;
                }
                while (j + 8 <= mA) { B8(a0, a1, sjA, j) j += 8; }
                while (k + 8 <= mB) { B8(b0, b1, sjB, k) k += 8; }
                while (j < mA && k < mB) {
                    int t = __shfl(sjA, j); int u = __shfl(sjB, k);
                    uint vA = xb[(size_t)t * 64 + lane];
                    uint vB = xb[(size_t)u * 64 + lane];
                    a0 += blo(vA); a1 += bhi(vA);
                    b0 += blo(vB); b1 += bhi(vB);
                    ++j; ++k;
                }
                while (j < mA) {
                    int t = __shfl(sjA, j++);
                    uint vA = xb[(size_t)t * 64 + lane];
                    a0 += blo(vA); a1 += bhi(vA);
                }
                while (k < mB) {
                    int u = __shfl(sjB, k++);
                    uint vB = xb[(size_t)u * 64 + lane];
                    b0 += blo(vB); b1 += bhi(vB);
                }
                iA += mA; iB += mB;
            }

            uint pkA = (uint)f2bf(a0) | ((uint)f2bf(a1) << 16);
            uint pkB = (uint)f2bf(b0) | ((uint)f2bf(b1) << 16);
            ((uint*)(agg + (size_t)nA * DD))[lane] = pkA;
            ((uint*)(agg + (size_t)nB * DD))[lane] = pkB;
        }
    }
    __threadfence();
    grid.sync();
    gemm_phase<1>(a.agg, a.Wbp, a.b1, nullptr, nullptr, nullptr, a.t1, a.stats, lw, red, lac);
    __threadfence();
    grid.sync();
    gemm_phase<2>(a.t1, a.Wbp + WPAD, a.b2, a.stats, a.g1, a.be1, a.t2, a.stats2, lw, red, lac);
    __threadfence();
    grid.sync();
    gemm_phase<3>(a.t2, a.Wbp + 2 * WPAD, nullptr, a.stats2, a.g2, a.be2, a.outp, nullptr, lw, red, lac);
}

extern "C" void kernel_launch(void* const* d_in, const int* in_sizes, int n_in,
                              void* d_out, int out_size, void* d_ws, size_t ws_size,
                              hipStream_t stream) {
    const float* x   = (const float*)d_in[0];
    const int* ei    = (const int*)d_in[1];
    const float* W1  = (const float*)d_in[2];
    const float* b1  = (const float*)d_in[3];
    const float* g1  = (const float*)d_in[4];
    const float* be1 = (const float*)d_in[5];
    const float* W2  = (const float*)d_in[6];
    const float* b2  = (const float*)d_in[7];
    const float* g2  = (const float*)d_in[8];
    const float* be2 = (const float*)d_in[9];
    const float* W3  = (const float*)d_in[10];

    float* stats  = (float*)d_ws;                 // SREP*256 for layer1
    float* stats2 = stats + SREP * 256;           // SREP*256 for layer2
    int* ghistP   = (int*)(stats2 + SREP * 256);
    int* gcurP    = ghistP + NCB * 16;
    ushort* Wbp   = (ushort*)(gcurP + NCB * 16);
    int* rowp     = (int*)(Wbp + 3 * WPAD);
    uint* buck    = (uint*)(rowp + NCB * 512 + 4);
    int* csr      = (int*)(buck + NE);
    ushort* agg   = (ushort*)(((uintptr_t)(csr + NE) + 15) & ~(uintptr_t)15);
    uint* xb     = (uint*)d_out;
    ushort* t1   = (ushort*)d_out + (size_t)NN * DD;
    ushort* t2   = agg;
    float* outp  = (float*)d_out;

    // cooperative grid size: query once, clamp to [256, 1024]
    static int gblocks = 0;
    if (gblocks == 0) {
        int nb = 0;
        hipOccupancyMaxActiveBlocksPerMultiprocessor(&nb, k_tail, 256, 0);
        if (nb < 1) nb = 1;
        if (nb > 4) nb = 4;
        gblocks = nb * 256;
    }

    hipMemsetAsync(stats, 0, (2 * SREP * 256) * sizeof(float) + 2 * NCB * 16 * sizeof(int), stream);
    k_xbh<<<NTILE, 256, 0, stream>>>(x, xb, ei, ghistP, W1, W2, W3, Wbp);
    k_cscatter<<<NTILEC, 256, 0, stream>>>(ei, ghistP, gcurP, buck);
    k_fsort<<<NCB, 256, 0, stream>>>(buck, ghistP, csr, rowp);

    TailArgs ha;
    ha.xb = xb; ha.rowp = rowp; ha.csr = csr; ha.agg = agg;
    ha.Wbp = Wbp;
    ha.b1 = b1; ha.b2 = b2;
    ha.g1 = g1; ha.be1 = be1; ha.g2 = g2; ha.be2 = be2;
    ha.t1 = t1; ha.t2 = t2; ha.outp = outp;
    ha.stats = stats; ha.stats2 = stats2;
    void* kargs[] = { (void*)&ha };
    hipLaunchCooperativeKernel((const void*)k_tail, dim3(gblocks), dim3(256),
                               kargs, 0, stream);
}

// Round 12
// 357.582 us; speedup vs baseline: 2.5209x; 2.5209x over previous
//
#include <hip/hip_runtime.h>

#define NN 100000
#define NE 1600000
#define DD 128
#define NCB 196     // coarse buckets, 512 nodes each (dst >> 9)
#define TILE 2048   // edges per xbh hist tile
#define NTILE 782   // ceil(NE/TILE)
#define TILEC 4096  // edges per cscatter tile (long write segments)
#define NTILEC 391  // ceil(NE/TILEC)
#define FCAP 12288  // fsort LDS edge capacity (mean 8163, +45 sigma)
#define SREP 32     // stats replicas (kills global-atomic line contention)
#define WPAD 17408  // padded bf16 W: 128 rows * 136 ushorts
#define GROWS 256   // rows per GEMM block for gemm2/3 (4 sub-tiles of 64)

typedef __attribute__((ext_vector_type(8))) short bf16x8;
typedef __attribute__((ext_vector_type(4))) float f32x4;

union u4bf8 { uint4 u; bf16x8 v; };

__device__ __forceinline__ ushort f2bf(float f) {
    union { float f; uint i; } v; v.f = f;
    uint i = v.i;
    return (ushort)((i + 0x7fffu + ((i >> 16) & 1u)) >> 16);
}
__device__ __forceinline__ float bf2f(ushort u) {
    union { uint i; float f; } v; v.i = ((uint)u) << 16; return v.f;
}
__device__ __forceinline__ float blo(uint v) { return bf2f((ushort)(v & 0xffffu)); }
__device__ __forceinline__ float bhi(uint v) { return bf2f((ushort)(v >> 16)); }

// fused: bf16 conversion of x -> xb + coarse dst histogram + bf16 W prep
__global__ __launch_bounds__(256) void k_xbh(const float* __restrict__ x,
                                             uint* __restrict__ xb,
                                             const int* __restrict__ ei,
                                             int* __restrict__ ghistP,
                                             const float* __restrict__ W1,
                                             const float* __restrict__ W2,
                                             const float* __restrict__ W3,
                                             ushort* __restrict__ Wbp) {
    __shared__ int h[NCB];
    int t = threadIdx.x;
    if (t < NCB) h[t] = 0;
    __syncthreads();
    int base = blockIdx.x * TILE;
#pragma unroll
    for (int i = 0; i < 8; ++i) {
        int e = base + i * 256 + t;
        if (e < NE) atomicAdd(&h[ei[NE + e] >> 9], 1);
    }
    int gid = blockIdx.x * 256 + t;
#pragma unroll
    for (int i = 0; i < 8; ++i) {
        int item = i * (NTILE * 256) + gid;
        if (item < NN * 16) {
            int n = item >> 4, q = item & 15;
            const float* xp = x + (size_t)n * DD + q * 8;
            float4 a = *(const float4*)xp;
            float4 b = *(const float4*)(xp + 4);
            uint4 pk;
            pk.x = (uint)f2bf(a.x) | ((uint)f2bf(a.y) << 16);
            pk.y = (uint)f2bf(a.z) | ((uint)f2bf(a.w) << 16);
            pk.z = (uint)f2bf(b.x) | ((uint)f2bf(b.y) << 16);
            pk.w = (uint)f2bf(b.z) | ((uint)f2bf(b.w) << 16);
            *(uint4*)(xb + (size_t)n * 64 + q * 4) = pk;
        }
    }
    // first 24 blocks also convert W1|W2|W3 (f32) into padded bf16 (136-stride)
    int c = gid;
    if (c < 6144) {
        int l = c >> 11;             // 2048 8-float chunks per 128x128 layer
        int cc = c & 2047;
        int r = cc >> 4, c8 = (cc & 15) * 8;
        const float* Wl = (l == 0) ? W1 : (l == 1) ? W2 : W3;
        const float* p = Wl + r * DD + c8;
        float4 a = *(const float4*)p;
        float4 b = *(const float4*)(p + 4);
        uint4 pk;
        pk.x = (uint)f2bf(a.x) | ((uint)f2bf(a.y) << 16);
        pk.y = (uint)f2bf(a.z) | ((uint)f2bf(a.w) << 16);
        pk.z = (uint)f2bf(b.x) | ((uint)f2bf(b.y) << 16);
        pk.w = (uint)f2bf(b.z) | ((uint)f2bf(b.w) << 16);
        *(uint4*)&Wbp[(size_t)l * WPAD + r * 136 + c8] = pk;
    }
    __syncthreads();
    if (t < NCB && h[t] > 0) atomicAdd(&ghistP[t * 16], h[t]);
}

// bucketize edges by coarse dst; packed val = src | (dst&511)<<17
// bucket bases computed by LOCAL scan of ghistP; cursors start at 0 (memset).
__global__ __launch_bounds__(256) void k_cscatter(const int* __restrict__ ei,
                                                  const int* __restrict__ ghistP,
                                                  int* __restrict__ gcurP,
                                                  uint* __restrict__ buck) {
    __shared__ int h[NCB];
    __shared__ int tb[NCB];
    __shared__ int sh[256];
    int t = threadIdx.x;
    if (t < NCB) h[t] = 0;
    __syncthreads();
    int base = blockIdx.x * TILEC;
    uint vv[16]; int bb[16]; int rr[16];
#pragma unroll
    for (int i = 0; i < 16; ++i) {
        int e = base + i * 256 + t;
        bb[i] = -1;
        if (e < NE) {
            int s = ei[e], d = ei[NE + e];
            int b = d >> 9;
            bb[i] = b;
            vv[i] = (uint)s | ((uint)(d & 511) << 17);
            rr[i] = atomicAdd(&h[b], 1);
        }
    }
    __syncthreads();
    int my = (t < NCB) ? ghistP[t * 16] : 0;
    sh[t] = my;
    __syncthreads();
    for (int o = 1; o < 256; o <<= 1) {
        int u = (t >= o) ? sh[t - o] : 0;
        __syncthreads();
        sh[t] += u;
        __syncthreads();
    }
    if (t < NCB && h[t] > 0)
        tb[t] = (sh[t] - my) + atomicAdd(&gcurP[t * 16], h[t]);
    __syncthreads();
#pragma unroll
    for (int i = 0; i < 16; ++i) {
        if (bb[i] >= 0) buck[tb[bb[i]] + rr[i]] = vv[i];
    }
}

// one block per coarse bucket: bases from local scan, segment staged in LDS,
// fine 512-node hist + scan, write rowp, scatter into node-sorted csr
__global__ __launch_bounds__(256) void k_fsort(const uint* __restrict__ buck,
                                               const int* __restrict__ ghistP,
                                               int* __restrict__ csr,
                                               int* __restrict__ rowp) {
    __shared__ uint ebuf[FCAP];
    __shared__ int cnt[512];
    __shared__ int sd[256];
    __shared__ int sh[256];
    int c = blockIdx.x, t = threadIdx.x;
    cnt[t] = 0; cnt[t + 256] = 0;
    int my = (t < NCB) ? ghistP[t * 16] : 0;
    sh[t] = my;
    __syncthreads();
    for (int o = 1; o < 256; o <<= 1) {
        int u = (t >= o) ? sh[t - o] : 0;
        __syncthreads();
        sh[t] += u;
        __syncthreads();
    }
    int s1 = sh[c];
    int hc = ghistP[c * 16];
    int s0 = s1 - hc;
    int len = hc;
    int cap = (len < FCAP) ? len : FCAP;
    for (int i = t; i < cap; i += 256) ebuf[i] = buck[s0 + i];
    __syncthreads();
    for (int i = t; i < len; i += 256) {
        uint v = (i < FCAP) ? ebuf[i] : buck[s0 + i];
        atomicAdd(&cnt[(v >> 17) & 511], 1);
    }
    __syncthreads();
    int p = cnt[2 * t], q = cnt[2 * t + 1];
    sd[t] = p + q;
    __syncthreads();
    for (int o = 1; o < 256; o <<= 1) {
        int u = (t >= o) ? sd[t - o] : 0;
        __syncthreads();
        sd[t] += u;
        __syncthreads();
    }
    int base = sd[t] - (p + q);
    rowp[c * 512 + 2 * t]     = s0 + base;
    rowp[c * 512 + 2 * t + 1] = s0 + base + p;
    __syncthreads();
    cnt[2 * t] = base;
    cnt[2 * t + 1] = base + p;
    __syncthreads();
    for (int i = t; i < len; i += 256) {
        uint v = (i < FCAP) ? ebuf[i] : buck[s0 + i];
        int ld = (int)((v >> 17) & 511u);
        int pos = atomicAdd(&cnt[ld], 1);
        csr[s0 + pos] = (int)(v & 0x1FFFFu);
    }
}

#define B8(ACC0, ACC1, SJ, J)                                               \
    {                                                                       \
        int s0 = __shfl(SJ, J),     s1 = __shfl(SJ, J + 1);                 \
        int s2 = __shfl(SJ, J + 2), s3 = __shfl(SJ, J + 3);                 \
        int s4 = __shfl(SJ, J + 4), s5 = __shfl(SJ, J + 5);                 \
        int s6 = __shfl(SJ, J + 6), s7 = __shfl(SJ, J + 7);                 \
        uint v0 = xb[(size_t)s0 * 64 + lane], v1 = xb[(size_t)s1 * 64 + lane]; \
        uint v2 = xb[(size_t)s2 * 64 + lane], v3 = xb[(size_t)s3 * 64 + lane]; \
        uint v4 = xb[(size_t)s4 * 64 + lane], v5 = xb[(size_t)s5 * 64 + lane]; \
        uint v6 = xb[(size_t)s6 * 64 + lane], v7 = xb[(size_t)s7 * 64 + lane]; \
        ACC0 += blo(v0) + blo(v1) + blo(v2) + blo(v3)                       \
              + blo(v4) + blo(v5) + blo(v6) + blo(v7);                      \
        ACC1 += bhi(v0) + bhi(v1) + bhi(v2) + bhi(v3)                       \
              + bhi(v4) + bhi(v5) + bhi(v6) + bhi(v7);                      \
    }

// FUSED gather + GEMM1: grid = 1563 blocks x 64 rows. Each wave gathers its
// OWN 16 A-rows (8 interleaved pairs, 16-deep MLP), writes them to agg
// (read back same-wave -> L1-hot, no cross-wave/block coherence needed),
// then runs the unchanged 64-row MFMA tile. 4 blocks/CU = 16 waves/CU during
// gather (matches standalone gather's measured occupancy).
__global__ __launch_bounds__(256) void k_gg1(const uint* __restrict__ xb,
                                             const int* __restrict__ rowp,
                                             const int* __restrict__ csr,
                                             ushort* __restrict__ agg,
                                             const ushort* __restrict__ Wp,
                                             const float* __restrict__ bias,
                                             ushort* __restrict__ Out16,
                                             float* __restrict__ statsOut) {
    __shared__ __align__(16) ushort lw[DD * 136];
    __shared__ float red[2][4][DD];
    int tid = threadIdx.x, wave = tid >> 6, lane = tid & 63;

    // ---- gather phase: wave's own 16 rows, pairs (i, i+8) ----
    int nbase = blockIdx.x * 64 + wave * 16;
    for (int i = 0; i < 8; ++i) {
        int nA = nbase + i, nB = nbase + i + 8;
        if (nA >= NN) break;
        bool okB = (nB < NN);
        uint sA = xb[(size_t)nA * 64 + lane];
        float a0 = blo(sA), a1 = bhi(sA);
        float b0 = 0.f, b1 = 0.f;
        int iA = rowp[nA], eA = rowp[nA + 1];
        int iB = 0, eB = 0;
        if (okB) {
            uint sB = xb[(size_t)nB * 64 + lane];
            b0 = blo(sB); b1 = bhi(sB);
            iB = rowp[nB]; eB = rowp[nB + 1];
        }

        while (iA < eA || iB < eB) {
            int mA = eA - iA; if (mA > 64) mA = 64; if (mA < 0) mA = 0;
            int mB = eB - iB; if (mB > 64) mB = 64; if (mB < 0) mB = 0;
            int sjA = (lane < mA) ? csr[iA + lane] : 0;
            int sjB = (lane < mB) ? csr[iB + lane] : 0;
            int j = 0, k = 0;
            while (j + 8 <= mA && k + 8 <= mB) {
                int t0 = __shfl(sjA, j),     t1 = __shfl(sjA, j + 1);
                int t2 = __shfl(sjA, j + 2), t3 = __shfl(sjA, j + 3);
                int t4 = __shfl(sjA, j + 4), t5 = __shfl(sjA, j + 5);
                int t6 = __shfl(sjA, j + 6), t7 = __shfl(sjA, j + 7);
                int u0 = __shfl(sjB, k),     u1 = __shfl(sjB, k + 1);
                int u2 = __shfl(sjB, k + 2), u3 = __shfl(sjB, k + 3);
                int u4 = __shfl(sjB, k + 4), u5 = __shfl(sjB, k + 5);
                int u6 = __shfl(sjB, k + 6), u7 = __shfl(sjB, k + 7);
                uint vA0 = xb[(size_t)t0 * 64 + lane], vA1 = xb[(size_t)t1 * 64 + lane];
                uint vA2 = xb[(size_t)t2 * 64 + lane], vA3 = xb[(size_t)t3 * 64 + lane];
                uint vA4 = xb[(size_t)t4 * 64 + lane], vA5 = xb[(size_t)t5 * 64 + lane];
                uint vA6 = xb[(size_t)t6 * 64 + lane], vA7 = xb[(size_t)t7 * 64 + lane];
                uint vB0 = xb[(size_t)u0 * 64 + lane], vB1 = xb[(size_t)u1 * 64 + lane];
                uint vB2 = xb[(size_t)u2 * 64 + lane], vB3 = xb[(size_t)u3 * 64 + lane];
                uint vB4 = xb[(size_t)u4 * 64 + lane], vB5 = xb[(size_t)u5 * 64 + lane];
                uint vB6 = xb[(size_t)u6 * 64 + lane], vB7 = xb[(size_t)u7 * 64 + lane];
                a0 += blo(vA0) + blo(vA1) + blo(vA2) + blo(vA3)
                    + blo(vA4) + blo(vA5) + blo(vA6) + blo(vA7);
                a1 += bhi(vA0) + bhi(vA1) + bhi(vA2) + bhi(vA3)
                    + bhi(vA4) + bhi(vA5) + bhi(vA6) + bhi(vA7);
                b0 += blo(vB0) + blo(vB1) + blo(vB2) + blo(vB3)
                    + blo(vB4) + blo(vB5) + blo(vB6) + blo(vB7);
                b1 += bhi(vB0) + bhi(vB1) + bhi(vB2) + bhi(vB3)
                    + bhi(vB4) + bhi(vB5) + bhi(vB6) + bhi(vB7);
                j += 8; k += 8;
            }
            while (j + 8 <= mA) { B8(a0, a1, sjA, j) j += 8; }
            while (k + 8 <= mB) { B8(b0, b1, sjB, k) k += 8; }
            while (j < mA && k < mB) {
                int t = __shfl(sjA, j); int u = __shfl(sjB, k);
                uint vA = xb[(size_t)t * 64 + lane];
                uint vB = xb[(size_t)u * 64 + lane];
                a0 += blo(vA); a1 += bhi(vA);
                b0 += blo(vB); b1 += bhi(vB);
                ++j; ++k;
            }
            while (j < mA) {
                int t = __shfl(sjA, j++);
                uint vA = xb[(size_t)t * 64 + lane];
                a0 += blo(vA); a1 += bhi(vA);
            }
            while (k < mB) {
                int u = __shfl(sjB, k++);
                uint vB = xb[(size_t)u * 64 + lane];
                b0 += blo(vB); b1 += bhi(vB);
            }
            iA += mA; iB += mB;
        }

        uint pkA = (uint)f2bf(a0) | ((uint)f2bf(a1) << 16);
        ((uint*)(agg + (size_t)nA * DD))[lane] = pkA;
        if (okB) {
            uint pkB = (uint)f2bf(b0) | ((uint)f2bf(b1) << 16);
            ((uint*)(agg + (size_t)nB * DD))[lane] = pkB;
        }
    }

    // ---- W staging ----
#pragma unroll
    for (int it = 0; it < 8; ++it) {
        int o8 = (it * 256 + tid) * 8;
        *(uint4*)&lw[o8] = *(const uint4*)&Wp[o8];
    }
    if (tid < 128) {
        int o8 = 16384 + tid * 8;
        *(uint4*)&lw[o8] = *(const uint4*)&Wp[o8];
    }
    __syncthreads();

    // ---- GEMM (64-row tile, MODE1: no pre-transform, bias, bf16 out, stats)
    int lm = lane & 15, quad = lane >> 4;
    int row0 = blockIdx.x * 64 + wave * 16;
    int arow = row0 + lm;
    int ar = (arow < NN) ? arow : 0;

    bf16x8 afrag[4];
#pragma unroll
    for (int kb = 0; kb < 4; ++kb) {
        u4bf8 u;
        u.u = *(const uint4*)(agg + (size_t)ar * DD + kb * 32 + quad * 8);
        afrag[kb] = u.v;    // same-wave read-back: L1-hot, program-ordered
    }

    f32x4 acc[8];
#pragma unroll
    for (int nt = 0; nt < 8; ++nt) {
        float bv = bias[nt * 16 + lm];
        acc[nt] = (f32x4){bv, bv, bv, bv};
    }

#pragma unroll
    for (int kb = 0; kb < 4; ++kb) {
#pragma unroll
        for (int nt = 0; nt < 8; ++nt) {
            bf16x8 bfrag = *(const bf16x8*)&lw[(nt * 16 + lm) * 136 + kb * 32 + quad * 8];
            acc[nt] = __builtin_amdgcn_mfma_f32_16x16x32_bf16(afrag[kb], bfrag, acc[nt], 0, 0, 0);
        }
    }

    float csum[8], csq[8];
#pragma unroll
    for (int nt = 0; nt < 8; ++nt) {
        int col = nt * 16 + lm;
        float s = 0.f, q = 0.f;
#pragma unroll
        for (int r = 0; r < 4; ++r) {
            int row = row0 + quad * 4 + r;
            float v = acc[nt][r];
            if (row < NN) {
                Out16[(size_t)row * DD + col] = f2bf(v);
                s += v;
                q += v * v;
            }
        }
        csum[nt] = s; csq[nt] = q;
    }

#pragma unroll
    for (int nt = 0; nt < 8; ++nt) {
        float s = csum[nt], q = csq[nt];
        s += __shfl_down(s, 16, 64); q += __shfl_down(q, 16, 64);
        s += __shfl_down(s, 32, 64); q += __shfl_down(q, 32, 64);
        if (quad == 0) {
            red[0][wave][nt * 16 + lm] = s;
            red[1][wave][nt * 16 + lm] = q;
        }
    }
    __syncthreads();
    if (tid < DD) {
        float S = red[0][0][tid] + red[0][1][tid] + red[0][2][tid] + red[0][3][tid];
        float Q = red[1][0][tid] + red[1][1][tid] + red[1][2][tid] + red[1][3][tid];
        int rep = (blockIdx.x & (SREP - 1)) << 8;
        atomicAdd(&statsOut[rep + tid], S);
        atomicAdd(&statsOut[rep + DD + tid], Q);
    }
}

// MODE 2: A = bf16 t1,  BN coefs from statsIn/g/be, relu(a*t+c), bias, bf16 out, stats
// MODE 3: A = bf16 t2,  same in-block BN, no bias, relu output, fp32 out, no stats
// GROWS=256 rows/block in 4 sub-tiles of 64; W staged once per block.
template <int MODE>
__global__ __launch_bounds__(256) void k_gemm(const ushort* __restrict__ Ain,
                                              const ushort* __restrict__ Wp,
                                              const float* __restrict__ bias,
                                              const float* __restrict__ statsIn,
                                              const float* __restrict__ g,
                                              const float* __restrict__ be,
                                              void* __restrict__ Outv,
                                              float* __restrict__ statsOut) {
    __shared__ __align__(16) ushort lw[DD * 136];
    __shared__ float red[2][4][DD];
    __shared__ float lac[2 * DD];

    int tid = threadIdx.x;
    int wave = tid >> 6, lane = tid & 63;
    int lm = lane & 15, quad = lane >> 4;

    // issue sub-tile-0 A loads first (overlap with W staging)
    int row00 = blockIdx.x * GROWS + wave * 16;
    int ar0 = (row00 + lm < NN) ? row00 + lm : 0;
    uint4 araw[4];
#pragma unroll
    for (int kb = 0; kb < 4; ++kb) {
        araw[kb] = *(const uint4*)(Ain + (size_t)ar0 * DD + kb * 32 + quad * 8);
    }

#pragma unroll
    for (int it = 0; it < 8; ++it) {
        int o8 = (it * 256 + tid) * 8;
        *(uint4*)&lw[o8] = *(const uint4*)&Wp[o8];
    }
    if (tid < 128) {                       // tail: 17408 = 8*2048 + 1024
        int o8 = 16384 + tid * 8;
        *(uint4*)&lw[o8] = *(const uint4*)&Wp[o8];
    }
    if (tid < DD) {
        float S = 0.f, Q = 0.f;
#pragma unroll
        for (int r = 0; r < SREP; ++r) {
            S += statsIn[(r << 8) + tid];
            Q += statsIn[(r << 8) + DD + tid];
        }
        float inv = 1.f / (float)NN;
        float mean = S * inv;
        float var = Q * inv - mean * mean;
        float a = g[tid] * rsqrtf(var + 1e-5f);
        lac[tid] = a;
        lac[DD + tid] = be[tid] - mean * a;
    }
    __syncthreads();

    ushort* Out16 = (ushort*)Outv;
    float* Out32 = (float*)Outv;

    float csum[8], csq[8];
#pragma unroll
    for (int nt = 0; nt < 8; ++nt) { csum[nt] = 0.f; csq[nt] = 0.f; }

#pragma unroll
    for (int sub = 0; sub < 4; ++sub) {
        int row0 = blockIdx.x * GROWS + sub * 64 + wave * 16;
        int arow = row0 + lm;
        int ar = (arow < NN) ? arow : 0;

        bf16x8 afrag[4];
#pragma unroll
        for (int kb = 0; kb < 4; ++kb) {
            int k0 = kb * 32 + quad * 8;
            u4bf8 u;
            if (sub == 0) u.u = araw[kb];
            else          u.u = *(const uint4*)(Ain + (size_t)ar * DD + k0);
            uint pk[4] = {u.u.x, u.u.y, u.u.z, u.u.w};
            bf16x8 af;
#pragma unroll
            for (int jj = 0; jj < 4; ++jj) {
                int k = k0 + jj * 2;
                float v0 = blo(pk[jj]);
                float v1 = bhi(pk[jj]);
                v0 = fmaxf(fmaf(v0, lac[k], lac[DD + k]), 0.f);
                v1 = fmaxf(fmaf(v1, lac[k + 1], lac[DD + k + 1]), 0.f);
                af[jj * 2]     = (short)f2bf(v0);
                af[jj * 2 + 1] = (short)f2bf(v1);
            }
            afrag[kb] = af;
        }

        f32x4 acc[8];
#pragma unroll
        for (int nt = 0; nt < 8; ++nt) {
            float bv = (MODE == 3) ? 0.f : bias[nt * 16 + lm];
            acc[nt] = (f32x4){bv, bv, bv, bv};
        }

#pragma unroll
        for (int kb = 0; kb < 4; ++kb) {
#pragma unroll
            for (int nt = 0; nt < 8; ++nt) {
                bf16x8 bfrag = *(const bf16x8*)&lw[(nt * 16 + lm) * 136 + kb * 32 + quad * 8];
                acc[nt] = __builtin_amdgcn_mfma_f32_16x16x32_bf16(afrag[kb], bfrag, acc[nt], 0, 0, 0);
            }
        }

#pragma unroll
        for (int nt = 0; nt < 8; ++nt) {
            int col = nt * 16 + lm;
#pragma unroll
            for (int r = 0; r < 4; ++r) {
                int row = row0 + quad * 4 + r;
                float v = acc[nt][r];
                if (MODE == 3) v = fmaxf(v, 0.f);
                if (row < NN) {
                    if constexpr (MODE == 3) Out32[(size_t)row * DD + col] = v;
                    else Out16[(size_t)row * DD + col] = f2bf(v);
                    csum[nt] += v;
                    csq[nt] += v * v;
                }
            }
        }
    }

    if constexpr (MODE != 3) {
#pragma unroll
        for (int nt = 0; nt < 8; ++nt) {
            float s = csum[nt], q = csq[nt];
            s += __shfl_down(s, 16, 64); q += __shfl_down(q, 16, 64);
            s += __shfl_down(s, 32, 64); q += __shfl_down(q, 32, 64);
            if (quad == 0) {
                red[0][wave][nt * 16 + lm] = s;
                red[1][wave][nt * 16 + lm] = q;
            }
        }
        __syncthreads();
        if (tid < DD) {
            float S = red[0][0][tid] + red[0][1][tid] + red[0][2][tid] + red[0][3][tid];
            float Q = red[1][0][tid] + red[1][1][tid] + red[1][2][tid] + red[1][3][tid];
            int rep = (blockIdx.x & (SREP - 1)) << 8;
            atomicAdd(&statsOut[rep + tid], S);
            atomicAdd(&statsOut[rep + DD + tid], Q);
        }
    }
}

extern "C" void kernel_launch(void* const* d_in, const int* in_sizes, int n_in,
                              void* d_out, int out_size, void* d_ws, size_t ws_size,
                              hipStream_t stream) {
    const float* x   = (const float*)d_in[0];
    const int* ei    = (const int*)d_in[1];
    const float* W1  = (const float*)d_in[2];
    const float* b1  = (const float*)d_in[3];
    const float* g1  = (const float*)d_in[4];
    const float* be1 = (const float*)d_in[5];
    const float* W2  = (const float*)d_in[6];
    const float* b2  = (const float*)d_in[7];
    const float* g2  = (const float*)d_in[8];
    const float* be2 = (const float*)d_in[9];
    const float* W3  = (const float*)d_in[10];

    // ws: stats[2*SREP*256] | ghistP[NCB*16] | gcurP[NCB*16] | Wbp bf16[3*WPAD]
    //   | rowp i32[NCB*512+4] | buck u32[NE] | csr i32[NE]
    //   | agg bf16[NN*DD] (16B-aligned, reused as t2)
    float* stats  = (float*)d_ws;                 // SREP*256 for layer1
    float* stats2 = stats + SREP * 256;           // SREP*256 for layer2
    int* ghistP   = (int*)(stats2 + SREP * 256);
    int* gcurP    = ghistP + NCB * 16;
    ushort* Wbp   = (ushort*)(gcurP + NCB * 16);
    int* rowp     = (int*)(Wbp + 3 * WPAD);
    uint* buck    = (uint*)(rowp + NCB * 512 + 4);
    int* csr      = (int*)(buck + NE);
    ushort* agg   = (ushort*)(((uintptr_t)(csr + NE) + 15) & ~(uintptr_t)15);
    // d_out: first half = xb (bf16 x copy), second half = t1
    uint* xb     = (uint*)d_out;
    ushort* t1   = (ushort*)d_out + (size_t)NN * DD;
    ushort* t2   = agg;
    float* outp  = (float*)d_out;

    int g1blk = (NN + 63) / 64;                   // 1563 fused gather+gemm1 blocks
    int gblk  = (NN + GROWS - 1) / GROWS;         // 391 blocks for gemm2/3
    hipMemsetAsync(stats, 0, (2 * SREP * 256) * sizeof(float) + 2 * NCB * 16 * sizeof(int), stream);
    k_xbh<<<NTILE, 256, 0, stream>>>(x, xb, ei, ghistP, W1, W2, W3, Wbp);
    k_cscatter<<<NTILEC, 256, 0, stream>>>(ei, ghistP, gcurP, buck);
    k_fsort<<<NCB, 256, 0, stream>>>(buck, ghistP, csr, rowp);
    k_gg1<<<g1blk, 256, 0, stream>>>(xb, rowp, csr, agg, Wbp, b1, t1, stats);
    k_gemm<2><<<gblk, 256, 0, stream>>>(t1, Wbp + WPAD, b2, stats, g1, be1, t2, stats2);
    k_gemm<3><<<gblk, 256, 0, stream>>>(t2, Wbp + 2 * WPAD, nullptr, stats2, g2, be2, outp, nullptr);
}

// Round 13
// 291.262 us; speedup vs baseline: 3.0949x; 1.2277x over previous
//
#include <hip/hip_runtime.h>

#define NN 100000
#define NE 1600000
#define DD 128
#define NCB 196     // coarse buckets, 512 nodes each (dst >> 9)
#define TILE 2048   // edges per xbh hist tile
#define NTILE 782   // ceil(NE/TILE)
#define TILEC 4096  // edges per cscatter tile (long write segments)
#define NTILEC 391  // ceil(NE/TILEC)
#define FCAP 12288  // fsort LDS edge capacity (mean 8163, +45 sigma)
#define SREP 32     // stats replicas (kills global-atomic line contention)
#define WPAD 17408  // padded bf16 W: 128 rows * 136 ushorts
#define GROWS 256   // rows per GEMM block (4 sub-tiles of 64)

typedef __attribute__((ext_vector_type(8))) short bf16x8;
typedef __attribute__((ext_vector_type(4))) float f32x4;

union u4bf8 { uint4 u; bf16x8 v; };

__device__ __forceinline__ ushort f2bf(float f) {
    union { float f; uint i; } v; v.f = f;
    uint i = v.i;
    return (ushort)((i + 0x7fffu + ((i >> 16) & 1u)) >> 16);
}
__device__ __forceinline__ float bf2f(ushort u) {
    union { uint i; float f; } v; v.i = ((uint)u) << 16; return v.f;
}
__device__ __forceinline__ float blo(uint v) { return bf2f((ushort)(v & 0xffffu)); }
__device__ __forceinline__ float bhi(uint v) { return bf2f((ushort)(v >> 16)); }

// fused: bf16 conversion of x -> xb + coarse dst histogram + bf16 W prep
__global__ __launch_bounds__(256) void k_xbh(const float* __restrict__ x,
                                             uint* __restrict__ xb,
                                             const int* __restrict__ ei,
                                             int* __restrict__ ghistP,
                                             const float* __restrict__ W1,
                                             const float* __restrict__ W2,
                                             const float* __restrict__ W3,
                                             ushort* __restrict__ Wbp) {
    __shared__ int h[NCB];
    int t = threadIdx.x;
    if (t < NCB) h[t] = 0;
    __syncthreads();
    int base = blockIdx.x * TILE;
#pragma unroll
    for (int i = 0; i < 8; ++i) {
        int e = base + i * 256 + t;
        if (e < NE) atomicAdd(&h[ei[NE + e] >> 9], 1);
    }
    int gid = blockIdx.x * 256 + t;
#pragma unroll
    for (int i = 0; i < 8; ++i) {
        int item = i * (NTILE * 256) + gid;
        if (item < NN * 16) {
            int n = item >> 4, q = item & 15;
            const float* xp = x + (size_t)n * DD + q * 8;
            float4 a = *(const float4*)xp;
            float4 b = *(const float4*)(xp + 4);
            uint4 pk;
            pk.x = (uint)f2bf(a.x) | ((uint)f2bf(a.y) << 16);
            pk.y = (uint)f2bf(a.z) | ((uint)f2bf(a.w) << 16);
            pk.z = (uint)f2bf(b.x) | ((uint)f2bf(b.y) << 16);
            pk.w = (uint)f2bf(b.z) | ((uint)f2bf(b.w) << 16);
            *(uint4*)(xb + (size_t)n * 64 + q * 4) = pk;
        }
    }
    // first 24 blocks also convert W1|W2|W3 (f32) into padded bf16 (136-stride)
    int c = gid;
    if (c < 6144) {
        int l = c >> 11;             // 2048 8-float chunks per 128x128 layer
        int cc = c & 2047;
        int r = cc >> 4, c8 = (cc & 15) * 8;
        const float* Wl = (l == 0) ? W1 : (l == 1) ? W2 : W3;
        const float* p = Wl + r * DD + c8;
        float4 a = *(const float4*)p;
        float4 b = *(const float4*)(p + 4);
        uint4 pk;
        pk.x = (uint)f2bf(a.x) | ((uint)f2bf(a.y) << 16);
        pk.y = (uint)f2bf(a.z) | ((uint)f2bf(a.w) << 16);
        pk.z = (uint)f2bf(b.x) | ((uint)f2bf(b.y) << 16);
        pk.w = (uint)f2bf(b.z) | ((uint)f2bf(b.w) << 16);
        *(uint4*)&Wbp[(size_t)l * WPAD + r * 136 + c8] = pk;
    }
    __syncthreads();
    if (t < NCB && h[t] > 0) atomicAdd(&ghistP[t * 16], h[t]);
}

// bucketize edges by coarse dst; packed val = src | (dst&511)<<17
// bucket bases computed by LOCAL scan of ghistP; cursors start at 0 (memset).
__global__ __launch_bounds__(256) void k_cscatter(const int* __restrict__ ei,
                                                  const int* __restrict__ ghistP,
                                                  int* __restrict__ gcurP,
                                                  uint* __restrict__ buck) {
    __shared__ int h[NCB];
    __shared__ int tb[NCB];
    __shared__ int sh[256];
    int t = threadIdx.x;
    if (t < NCB) h[t] = 0;
    __syncthreads();
    int base = blockIdx.x * TILEC;
    uint vv[16]; int bb[16]; int rr[16];
#pragma unroll
    for (int i = 0; i < 16; ++i) {
        int e = base + i * 256 + t;
        bb[i] = -1;
        if (e < NE) {
            int s = ei[e], d = ei[NE + e];
            int b = d >> 9;
            bb[i] = b;
            vv[i] = (uint)s | ((uint)(d & 511) << 17);
            rr[i] = atomicAdd(&h[b], 1);
        }
    }
    __syncthreads();
    int my = (t < NCB) ? ghistP[t * 16] : 0;
    sh[t] = my;
    __syncthreads();
    for (int o = 1; o < 256; o <<= 1) {
        int u = (t >= o) ? sh[t - o] : 0;
        __syncthreads();
        sh[t] += u;
        __syncthreads();
    }
    if (t < NCB && h[t] > 0)
        tb[t] = (sh[t] - my) + atomicAdd(&gcurP[t * 16], h[t]);
    __syncthreads();
#pragma unroll
    for (int i = 0; i < 16; ++i) {
        if (bb[i] >= 0) buck[tb[bb[i]] + rr[i]] = vv[i];
    }
}

// one block per coarse bucket: bases from local scan, segment staged in LDS,
// fine 512-node hist + scan, write rowp, scatter into node-sorted csr
__global__ __launch_bounds__(256) void k_fsort(const uint* __restrict__ buck,
                                               const int* __restrict__ ghistP,
                                               int* __restrict__ csr,
                                               int* __restrict__ rowp) {
    __shared__ uint ebuf[FCAP];
    __shared__ int cnt[512];
    __shared__ int sd[256];
    __shared__ int sh[256];
    int c = blockIdx.x, t = threadIdx.x;
    cnt[t] = 0; cnt[t + 256] = 0;
    int my = (t < NCB) ? ghistP[t * 16] : 0;
    sh[t] = my;
    __syncthreads();
    for (int o = 1; o < 256; o <<= 1) {
        int u = (t >= o) ? sh[t - o] : 0;
        __syncthreads();
        sh[t] += u;
        __syncthreads();
    }
    int s1 = sh[c];
    int hc = ghistP[c * 16];
    int s0 = s1 - hc;
    int len = hc;
    int cap = (len < FCAP) ? len : FCAP;
    for (int i = t; i < cap; i += 256) ebuf[i] = buck[s0 + i];
    __syncthreads();
    for (int i = t; i < len; i += 256) {
        uint v = (i < FCAP) ? ebuf[i] : buck[s0 + i];
        atomicAdd(&cnt[(v >> 17) & 511], 1);
    }
    __syncthreads();
    int p = cnt[2 * t], q = cnt[2 * t + 1];
    sd[t] = p + q;
    __syncthreads();
    for (int o = 1; o < 256; o <<= 1) {
        int u = (t >= o) ? sd[t - o] : 0;
        __syncthreads();
        sd[t] += u;
        __syncthreads();
    }
    int base = sd[t] - (p + q);
    rowp[c * 512 + 2 * t]     = s0 + base;
    rowp[c * 512 + 2 * t + 1] = s0 + base + p;
    __syncthreads();
    cnt[2 * t] = base;
    cnt[2 * t + 1] = base + p;
    __syncthreads();
    for (int i = t; i < len; i += 256) {
        uint v = (i < FCAP) ? ebuf[i] : buck[s0 + i];
        int ld = (int)((v >> 17) & 511u);
        int pos = atomicAdd(&cnt[ld], 1);
        csr[s0 + pos] = (int)(v & 0x1FFFFu);
    }
}

// one wave per TWO nodes (w and w+50000): 16-deep outstanding row loads.
#define B8(ACC0, ACC1, SJ, J)                                               \
    {                                                                       \
        int s0 = __shfl(SJ, J),     s1 = __shfl(SJ, J + 1);                 \
        int s2 = __shfl(SJ, J + 2), s3 = __shfl(SJ, J + 3);                 \
        int s4 = __shfl(SJ, J + 4), s5 = __shfl(SJ, J + 5);                 \
        int s6 = __shfl(SJ, J + 6), s7 = __shfl(SJ, J + 7);                 \
        uint v0 = xb[(size_t)s0 * 64 + lane], v1 = xb[(size_t)s1 * 64 + lane]; \
        uint v2 = xb[(size_t)s2 * 64 + lane], v3 = xb[(size_t)s3 * 64 + lane]; \
        uint v4 = xb[(size_t)s4 * 64 + lane], v5 = xb[(size_t)s5 * 64 + lane]; \
        uint v6 = xb[(size_t)s6 * 64 + lane], v7 = xb[(size_t)s7 * 64 + lane]; \
        ACC0 += blo(v0) + blo(v1) + blo(v2) + blo(v3)                       \
              + blo(v4) + blo(v5) + blo(v6) + blo(v7);                      \
        ACC1 += bhi(v0) + bhi(v1) + bhi(v2) + bhi(v3)                       \
              + bhi(v4) + bhi(v5) + bhi(v6) + bhi(v7);                      \
    }

__global__ __launch_bounds__(256) void k_gather(const uint* __restrict__ xb,
                                                const int* __restrict__ rowp,
                                                const int* __restrict__ csr,
                                                ushort* __restrict__ agg) {
    const int HALF = NN / 2;   // 50000
    int wave = threadIdx.x >> 6, lane = threadIdx.x & 63;
    int w = blockIdx.x * 4 + wave;
    if (w >= HALF) return;
    int nA = w, nB = w + HALF;
    uint sA = xb[(size_t)nA * 64 + lane];
    uint sB = xb[(size_t)nB * 64 + lane];
    float a0 = blo(sA), a1 = bhi(sA);
    float b0 = blo(sB), b1 = bhi(sB);
    int iA = rowp[nA], eA = rowp[nA + 1];
    int iB = rowp[nB], eB = rowp[nB + 1];

    while (iA < eA || iB < eB) {
        int mA = eA - iA; if (mA > 64) mA = 64; if (mA < 0) mA = 0;
        int mB = eB - iB; if (mB > 64) mB = 64; if (mB < 0) mB = 0;
        int sjA = (lane < mA) ? csr[iA + lane] : 0;
        int sjB = (lane < mB) ? csr[iB + lane] : 0;
        int j = 0, k = 0;
        while (j + 8 <= mA && k + 8 <= mB) {
            int t0 = __shfl(sjA, j),     t1 = __shfl(sjA, j + 1);
            int t2 = __shfl(sjA, j + 2), t3 = __shfl(sjA, j + 3);
            int t4 = __shfl(sjA, j + 4), t5 = __shfl(sjA, j + 5);
            int t6 = __shfl(sjA, j + 6), t7 = __shfl(sjA, j + 7);
            int u0 = __shfl(sjB, k),     u1 = __shfl(sjB, k + 1);
            int u2 = __shfl(sjB, k + 2), u3 = __shfl(sjB, k + 3);
            int u4 = __shfl(sjB, k + 4), u5 = __shfl(sjB, k + 5);
            int u6 = __shfl(sjB, k + 6), u7 = __shfl(sjB, k + 7);
            uint vA0 = xb[(size_t)t0 * 64 + lane], vA1 = xb[(size_t)t1 * 64 + lane];
            uint vA2 = xb[(size_t)t2 * 64 + lane], vA3 = xb[(size_t)t3 * 64 + lane];
            uint vA4 = xb[(size_t)t4 * 64 + lane], vA5 = xb[(size_t)t5 * 64 + lane];
            uint vA6 = xb[(size_t)t6 * 64 + lane], vA7 = xb[(size_t)t7 * 64 + lane];
            uint vB0 = xb[(size_t)u0 * 64 + lane], vB1 = xb[(size_t)u1 * 64 + lane];
            uint vB2 = xb[(size_t)u2 * 64 + lane], vB3 = xb[(size_t)u3 * 64 + lane];
            uint vB4 = xb[(size_t)u4 * 64 + lane], vB5 = xb[(size_t)u5 * 64 + lane];
            uint vB6 = xb[(size_t)u6 * 64 + lane], vB7 = xb[(size_t)u7 * 64 + lane];
            a0 += blo(vA0) + blo(vA1) + blo(vA2) + blo(vA3)
                + blo(vA4) + blo(vA5) + blo(vA6) + blo(vA7);
            a1 += bhi(vA0) + bhi(vA1) + bhi(vA2) + bhi(vA3)
                + bhi(vA4) + bhi(vA5) + bhi(vA6) + bhi(vA7);
            b0 += blo(vB0) + blo(vB1) + blo(vB2) + blo(vB3)
                + blo(vB4) + blo(vB5) + blo(vB6) + blo(vB7);
            b1 += bhi(vB0) + bhi(vB1) + bhi(vB2) + bhi(vB3)
                + bhi(vB4) + bhi(vB5) + bhi(vB6) + bhi(vB7);
            j += 8; k += 8;
        }
        while (j + 8 <= mA) { B8(a0, a1, sjA, j) j += 8; }
        while (k + 8 <= mB) { B8(b0, b1, sjB, k) k += 8; }
        while (j < mA && k < mB) {
            int t = __shfl(sjA, j); int u = __shfl(sjB, k);
            uint vA = xb[(size_t)t * 64 + lane];
            uint vB = xb[(size_t)u * 64 + lane];
            a0 += blo(vA); a1 += bhi(vA);
            b0 += blo(vB); b1 += bhi(vB);
            ++j; ++k;
        }
        while (j < mA) {
            int t = __shfl(sjA, j++);
            uint vA = xb[(size_t)t * 64 + lane];
            a0 += blo(vA); a1 += bhi(vA);
        }
        while (k < mB) {
            int u = __shfl(sjB, k++);
            uint vB = xb[(size_t)u * 64 + lane];
            b0 += blo(vB); b1 += bhi(vB);
        }
        iA += mA; iB += mB;
    }

    uint pkA = (uint)f2bf(a0) | ((uint)f2bf(a1) << 16);
    uint pkB = (uint)f2bf(b0) | ((uint)f2bf(b1) << 16);
    ((uint*)(agg + (size_t)nA * DD))[lane] = pkA;
    ((uint*)(agg + (size_t)nB * DD))[lane] = pkB;
}

// MODE 1: A = bf16 agg, no pre-transform, bias, bf16 out, emit colstats
// MODE 2: A = bf16 t1,  BN coefs from statsIn/g/be, relu(a*t+c), bias, bf16 out, stats
// MODE 3: A = bf16 t2,  same in-block BN, no bias, relu output, fp32 out, no stats
// GROWS=256 rows/block in 4 sub-tiles of 64; W staged once per block.
// A-tile raw loads for sub-tile 0 are issued BEFORE W staging (latency overlap).
template <int MODE>
__global__ __launch_bounds__(256) void k_gemm(const ushort* __restrict__ Ain,
                                              const ushort* __restrict__ Wp,
                                              const float* __restrict__ bias,
                                              const float* __restrict__ statsIn,
                                              const float* __restrict__ g,
                                              const float* __restrict__ be,
                                              void* __restrict__ Outv,
                                              float* __restrict__ statsOut) {
    __shared__ __align__(16) ushort lw[DD * 136];
    __shared__ float red[2][4][DD];
    __shared__ float lac[2 * DD];

    int tid = threadIdx.x;
    int wave = tid >> 6, lane = tid & 63;
    int lm = lane & 15, quad = lane >> 4;

    // issue sub-tile-0 A loads first (overlap with W staging)
    int row00 = blockIdx.x * GROWS + wave * 16;
    int ar0 = (row00 + lm < NN) ? row00 + lm : 0;
    uint4 araw[4];
#pragma unroll
    for (int kb = 0; kb < 4; ++kb) {
        araw[kb] = *(const uint4*)(Ain + (size_t)ar0 * DD + kb * 32 + quad * 8);
    }

#pragma unroll
    for (int it = 0; it < 8; ++it) {
        int o8 = (it * 256 + tid) * 8;
        *(uint4*)&lw[o8] = *(const uint4*)&Wp[o8];
    }
    if (tid < 128) {                       // tail: 17408 = 8*2048 + 1024
        int o8 = 16384 + tid * 8;
        *(uint4*)&lw[o8] = *(const uint4*)&Wp[o8];
    }
    if constexpr (MODE != 1) {
        if (tid < DD) {
            float S = 0.f, Q = 0.f;
#pragma unroll
            for (int r = 0; r < SREP; ++r) {
                S += statsIn[(r << 8) + tid];
                Q += statsIn[(r << 8) + DD + tid];
            }
            float inv = 1.f / (float)NN;
            float mean = S * inv;
            float var = Q * inv - mean * mean;
            float a = g[tid] * rsqrtf(var + 1e-5f);
            lac[tid] = a;
            lac[DD + tid] = be[tid] - mean * a;
        }
    }
    __syncthreads();

    ushort* Out16 = (ushort*)Outv;
    float* Out32 = (float*)Outv;

    float csum[8], csq[8];
#pragma unroll
    for (int nt = 0; nt < 8; ++nt) { csum[nt] = 0.f; csq[nt] = 0.f; }

#pragma unroll
    for (int sub = 0; sub < 4; ++sub) {
        int row0 = blockIdx.x * GROWS + sub * 64 + wave * 16;
        int arow = row0 + lm;
        int ar = (arow < NN) ? arow : 0;

        bf16x8 afrag[4];
#pragma unroll
        for (int kb = 0; kb < 4; ++kb) {
            int k0 = kb * 32 + quad * 8;
            u4bf8 u;
            if (sub == 0) u.u = araw[kb];
            else          u.u = *(const uint4*)(Ain + (size_t)ar * DD + k0);
            if constexpr (MODE == 1) {
                afrag[kb] = u.v;
            } else {
                uint pk[4] = {u.u.x, u.u.y, u.u.z, u.u.w};
                bf16x8 af;
#pragma unroll
                for (int jj = 0; jj < 4; ++jj) {
                    int k = k0 + jj * 2;
                    float v0 = blo(pk[jj]);
                    float v1 = bhi(pk[jj]);
                    v0 = fmaxf(fmaf(v0, lac[k], lac[DD + k]), 0.f);
                    v1 = fmaxf(fmaf(v1, lac[k + 1], lac[DD + k + 1]), 0.f);
                    af[jj * 2]     = (short)f2bf(v0);
                    af[jj * 2 + 1] = (short)f2bf(v1);
                }
                afrag[kb] = af;
            }
        }

        f32x4 acc[8];
#pragma unroll
        for (int nt = 0; nt < 8; ++nt) {
            float bv = (MODE == 3) ? 0.f : bias[nt * 16 + lm];
            acc[nt] = (f32x4){bv, bv, bv, bv};
        }

#pragma unroll
        for (int kb = 0; kb < 4; ++kb) {
#pragma unroll
            for (int nt = 0; nt < 8; ++nt) {
                bf16x8 bfrag = *(const bf16x8*)&lw[(nt * 16 + lm) * 136 + kb * 32 + quad * 8];
                acc[nt] = __builtin_amdgcn_mfma_f32_16x16x32_bf16(afrag[kb], bfrag, acc[nt], 0, 0, 0);
            }
        }

#pragma unroll
        for (int nt = 0; nt < 8; ++nt) {
            int col = nt * 16 + lm;
#pragma unroll
            for (int r = 0; r < 4; ++r) {
                int row = row0 + quad * 4 + r;
                float v = acc[nt][r];
                if (MODE == 3) v = fmaxf(v, 0.f);
                if (row < NN) {
                    if constexpr (MODE == 3) Out32[(size_t)row * DD + col] = v;
                    else Out16[(size_t)row * DD + col] = f2bf(v);
                    csum[nt] += v;
                    csq[nt] += v * v;
                }
            }
        }
    }

    if constexpr (MODE != 3) {
#pragma unroll
        for (int nt = 0; nt < 8; ++nt) {
            float s = csum[nt], q = csq[nt];
            s += __shfl_down(s, 16, 64); q += __shfl_down(q, 16, 64);
            s += __shfl_down(s, 32, 64); q += __shfl_down(q, 32, 64);
            if (quad == 0) {
                red[0][wave][nt * 16 + lm] = s;
                red[1][wave][nt * 16 + lm] = q;
            }
        }
        __syncthreads();
        if (tid < DD) {
            float S = red[0][0][tid] + red[0][1][tid] + red[0][2][tid] + red[0][3][tid];
            float Q = red[1][0][tid] + red[1][1][tid] + red[1][2][tid] + red[1][3][tid];
            int rep = (blockIdx.x & (SREP - 1)) << 8;
            atomicAdd(&statsOut[rep + tid], S);
            atomicAdd(&statsOut[rep + DD + tid], Q);
        }
    }
}

extern "C" void kernel_launch(void* const* d_in, const int* in_sizes, int n_in,
                              void* d_out, int out_size, void* d_ws, size_t ws_size,
                              hipStream_t stream) {
    const float* x   = (const float*)d_in[0];
    const int* ei    = (const int*)d_in[1];
    const float* W1  = (const float*)d_in[2];
    const float* b1  = (const float*)d_in[3];
    const float* g1  = (const float*)d_in[4];
    const float* be1 = (const float*)d_in[5];
    const float* W2  = (const float*)d_in[6];
    const float* b2  = (const float*)d_in[7];
    const float* g2  = (const float*)d_in[8];
    const float* be2 = (const float*)d_in[9];
    const float* W3  = (const float*)d_in[10];

    // ws: stats[2*SREP*256] | ghistP[NCB*16] | gcurP[NCB*16] | Wbp bf16[3*WPAD]
    //   | rowp i32[NCB*512+4] | buck u32[NE] | csr i32[NE]
    //   | agg bf16[NN*DD] (16B-aligned, reused as t2)
    float* stats  = (float*)d_ws;                 // SREP*256 for layer1
    float* stats2 = stats + SREP * 256;           // SREP*256 for layer2
    int* ghistP   = (int*)(stats2 + SREP * 256);
    int* gcurP    = ghistP + NCB * 16;
    ushort* Wbp   = (ushort*)(gcurP + NCB * 16);
    int* rowp     = (int*)(Wbp + 3 * WPAD);
    uint* buck    = (uint*)(rowp + NCB * 512 + 4);
    int* csr      = (int*)(buck + NE);
    ushort* agg   = (ushort*)(((uintptr_t)(csr + NE) + 15) & ~(uintptr_t)15);
    // d_out: first half = xb (bf16 x copy), second half = t1
    uint* xb     = (uint*)d_out;
    ushort* t1   = (ushort*)d_out + (size_t)NN * DD;
    ushort* t2   = agg;
    float* outp  = (float*)d_out;

    int gblk = (NN + GROWS - 1) / GROWS;          // 391 blocks, all co-resident
    // one memset: stats (both layers) + ghistP + gcurP (contiguous)
    hipMemsetAsync(stats, 0, (2 * SREP * 256) * sizeof(float) + 2 * NCB * 16 * sizeof(int), stream);
    k_xbh<<<NTILE, 256, 0, stream>>>(x, xb, ei, ghistP, W1, W2, W3, Wbp);
    k_cscatter<<<NTILEC, 256, 0, stream>>>(ei, ghistP, gcurP, buck);
    k_fsort<<<NCB, 256, 0, stream>>>(buck, ghistP, csr, rowp);
    k_gather<<<(NN / 2 + 3) / 4, 256, 0, stream>>>(xb, rowp, csr, agg);
    k_gemm<1><<<gblk, 256, 0, stream>>>(agg, Wbp, b1, nullptr, nullptr, nullptr, t1, stats);
    k_gemm<2><<<gblk, 256, 0, stream>>>(t1, Wbp + WPAD, b2, stats, g1, be1, t2, stats2);
    k_gemm<3><<<gblk, 256, 0, stream>>>(t2, Wbp + 2 * WPAD, nullptr, stats2, g2, be2, outp, nullptr);
}